// Round 14
// baseline (417.284 us; speedup 1.0000x reference)
//
#include <hip/hip_runtime.h>
#include <hip/hip_bf16.h>
#include <float.h>
#include <limits.h>

#define NPTS 8192
#define NB 2
#define NQ (NB * NPTS)   // 16384
#define KNN 16
#define NPATCHES 64      // B * NUM_PATCHES, 256 points each

// ---------------- LAPACK float32 helpers (faithful ports) ----------------

__device__ __forceinline__ float f_sign(float a, float b) {
    float aa = fabsf(a);
    return (b >= 0.0f) ? aa : -aa;
}

__device__ __forceinline__ float slapy2f(float x, float y) {
#pragma clang fp contract(off)
    float xa = fabsf(x), ya = fabsf(y);
    float w = fmaxf(xa, ya), z = fminf(xa, ya);
    if (z == 0.0f) return w;
    float q = z / w;
    return w * sqrtf(1.0f + q * q);
}

// LAPACK >= 3.10 slartg convention (r carries sign of f)
__device__ __forceinline__ void slartgf(float f, float g, float* cs, float* sn, float* r) {
#pragma clang fp contract(off)
    if (g == 0.0f) { *cs = 1.0f; *sn = 0.0f; *r = f; }
    else if (f == 0.0f) { *cs = 0.0f; *sn = (g >= 0.0f) ? 1.0f : -1.0f; *r = fabsf(g); }
    else {
        float d = sqrtf(f * f + g * g);
        *cs = fabsf(f) / d;
        float rr = f_sign(d, f);
        *sn = g / rr;
        *r = rr;
    }
}

__device__ void slaev2f(float a, float b, float c, float* rt1, float* rt2,
                        float* cs1, float* sn1) {
#pragma clang fp contract(off)
    float sm = a + c, df = a - c;
    float adf = fabsf(df);
    float tb = b + b;
    float ab = fabsf(tb);
    float acmx, acmn;
    if (fabsf(a) > fabsf(c)) { acmx = a; acmn = c; } else { acmx = c; acmn = a; }
    float rt;
    if (adf > ab)      { float q = ab / adf; rt = adf * sqrtf(1.0f + q * q); }
    else if (adf < ab) { float q = adf / ab; rt = ab * sqrtf(1.0f + q * q); }
    else               { rt = ab * sqrtf(2.0f); }
    int sgn1;
    if (sm < 0.0f) {
        *rt1 = 0.5f * (sm - rt); sgn1 = -1;
        *rt2 = (acmx / *rt1) * acmn - (b / *rt1) * b;
    } else if (sm > 0.0f) {
        *rt1 = 0.5f * (sm + rt); sgn1 = 1;
        *rt2 = (acmx / *rt1) * acmn - (b / *rt1) * b;
    } else {
        *rt1 = 0.5f * rt; *rt2 = -0.5f * rt; sgn1 = 1;
    }
    float cs; int sgn2;
    if (df >= 0.0f) { cs = df + rt; sgn2 = 1; } else { cs = df - rt; sgn2 = -1; }
    float acs = fabsf(cs);
    if (acs > ab) {
        float ct = -tb / cs;
        *sn1 = 1.0f / sqrtf(1.0f + ct * ct);
        *cs1 = ct * (*sn1);
    } else {
        if (ab == 0.0f) { *cs1 = 1.0f; *sn1 = 0.0f; }
        else {
            float tn = -cs / tb;
            *cs1 = 1.0f / sqrtf(1.0f + tn * tn);
            *sn1 = tn * (*cs1);
        }
    }
    if (sgn1 == sgn2) { float tn = *cs1; *cs1 = -(*sn1); *sn1 = tn; }
}

// Faithful ssyevd(jobz='V', uplo='L') for 3x3: ssytd2 + ssteqr('I') + sormtr.
// cov = [c00, c10, c11, c20, c21, c22] (lower triangle).
// W: 27-float per-thread scratch (LDS). evals ascending; nvec = eigvec col 0.
__device__ void eigh3_lapack(const float cov[6], float* W, float evals[3], float nvec[3]) {
#pragma clang fp contract(off)
    const float eps = 5.9604644775390625e-08f;   // slamch('E') fp32
    const float eps2 = eps * eps;
    const float safmin = 1.1754943508222875e-38f;
#define D_(i)  W[(i)]
#define E_(i)  W[4 + (i)]
#define WC_(i) W[8 + (i)]
#define WS_(i) W[12 + (i)]
#define ZZ(r, cf) W[16 + ((cf) - 1) * 3 + (r)]
    float a00 = cov[0], a10 = cov[1], a11 = cov[2], a20 = cov[3], a21 = cov[4], a22 = cov[5];

    // ---- ssytd2 (lower), n=3: one reflector annihilating A(3,1)
    float tau, v2, beta;
    {
        float alpha = a10;
        float xnorm = fabsf(a20);
        if (xnorm == 0.0f) { tau = 0.0f; v2 = 0.0f; beta = alpha; }
        else {
            beta = -f_sign(slapy2f(alpha, xnorm), alpha);
            tau = (beta - alpha) / beta;
            v2 = a20 * (1.0f / (alpha - beta));
            // ssymv (reference BLAS association): p0 = tau*a11 + tau*(a21*v2)
            float p0 = tau * a11 + tau * (a21 * v2);
            float p1 = tau * a21 + (tau * v2) * a22;
            float al = -0.5f * tau * (p0 + p1 * v2);
            float w0 = p0 + al;
            float w1 = p1 + al * v2;
            a11 = (a11 - w0) - w0;
            a21 = (a21 - v2 * w0) - w1;
            a22 = (a22 - v2 * w1) - w1 * v2;
        }
    }
    D_(1) = a00; D_(2) = a11; D_(3) = a22;
    E_(1) = beta; E_(2) = a21;
    for (int cf = 1; cf <= 3; ++cf)
        for (int r0 = 0; r0 < 3; ++r0)
            ZZ(r0, cf) = (r0 == cf - 1) ? 1.0f : 0.0f;

    // ---- ssteqr('I', n=3)
    const int n = 3;
    int nmaxit = n * 30, jtot = 0, l1 = 1;
    int l, m, lsv, lend, lendsv;
    float p, g, r, c, s, f, b;

L10:
    if (l1 > n) goto L160;
    if (l1 > 1) E_(l1 - 1) = 0.0f;
    m = n;
    if (l1 <= n - 1) {
        for (int mi = l1; mi <= n - 1; ++mi) {
            float tst = fabsf(E_(mi));
            if (tst == 0.0f) { m = mi; goto L30; }
            if (tst <= (sqrtf(fabsf(D_(mi))) * sqrtf(fabsf(D_(mi + 1)))) * eps) {
                E_(mi) = 0.0f; m = mi; goto L30;
            }
        }
        m = n;
    }
L30:
    l = l1; lsv = l; lend = m; lendsv = lend; l1 = m + 1;
    if (lend == l) goto L10;
    {
        float anorm = fabsf(D_(lend));
        for (int i2 = l; i2 <= lend - 1; ++i2) {
            anorm = fmaxf(anorm, fabsf(D_(i2)));
            anorm = fmaxf(anorm, fabsf(E_(i2)));
        }
        if (anorm == 0.0f) goto L10;
        // scaling branch omitted: cov magnitudes are O(1e-3..1e2), far inside [ssfmin, ssfmax]
    }
    if (fabsf(D_(lend)) < fabsf(D_(l))) { lend = lsv; l = lendsv; }
    if (lend > l) goto L40;
    goto L90;

    // ---------- QL iteration ----------
L40:
    if (l != lend) {
        m = lend;
        for (int mi = l; mi <= lend - 1; ++mi) {
            float tst = fabsf(E_(mi)); tst = tst * tst;
            if (tst <= (eps2 * fabsf(D_(mi))) * fabsf(D_(mi + 1)) + safmin) { m = mi; goto L60; }
        }
    } else { m = lend; }
L60:
    if (m < lend) E_(m) = 0.0f;
    p = D_(l);
    if (m == l) goto L80;
    if (m == l + 1) {
        float rt1, rt2, c2, s2;
        slaev2f(D_(l), E_(l), D_(l + 1), &rt1, &rt2, &c2, &s2);
        for (int r2 = 0; r2 < 3; ++r2) {
            float temp = ZZ(r2, l + 1);
            ZZ(r2, l + 1) = c2 * temp - s2 * ZZ(r2, l);
            ZZ(r2, l)     = s2 * temp + c2 * ZZ(r2, l);
        }
        D_(l) = rt1; D_(l + 1) = rt2; E_(l) = 0.0f;
        l += 2;
        if (l <= lend) goto L40;
        goto L140;
    }
    if (jtot == nmaxit) goto L140;
    jtot++;
    g = (D_(l + 1) - p) / (2.0f * E_(l));
    r = slapy2f(g, 1.0f);
    g = D_(m) - p + (E_(l) / (g + f_sign(r, g)));
    s = 1.0f; c = 1.0f; p = 0.0f;
    for (int i2 = m - 1; i2 >= l; --i2) {
        f = s * E_(i2); b = c * E_(i2);
        slartgf(g, f, &c, &s, &r);
        if (i2 != m - 1) E_(i2 + 1) = r;
        g = D_(i2 + 1) - p;
        r = (D_(i2) - g) * s + 2.0f * c * b;
        p = s * r;
        D_(i2 + 1) = g + p;
        g = c * r - b;
        WC_(i2) = c; WS_(i2) = -s;
    }
    {
        int mm = m - l + 1;
        for (int J = mm - 1; J >= 1; --J) {
            float ct = WC_(l + J - 1), st = WS_(l + J - 1);
            for (int r2 = 0; r2 < 3; ++r2) {
                float temp = ZZ(r2, l + J);
                ZZ(r2, l + J)     = ct * temp - st * ZZ(r2, l + J - 1);
                ZZ(r2, l + J - 1) = st * temp + ct * ZZ(r2, l + J - 1);
            }
        }
    }
    D_(l) = D_(l) - p;
    E_(l) = g;
    goto L40;
L80:
    D_(l) = p;
    l++;
    if (l <= lend) goto L40;
    goto L140;

    // ---------- QR iteration ----------
L90:
    if (l != lend) {
        m = lend;
        for (int mi = l; mi >= lend + 1; --mi) {
            float tst = fabsf(E_(mi - 1)); tst = tst * tst;
            if (tst <= (eps2 * fabsf(D_(mi))) * fabsf(D_(mi - 1)) + safmin) { m = mi; goto L110; }
        }
    } else { m = lend; }
L110:
    if (m > lend) E_(m - 1) = 0.0f;
    p = D_(l);
    if (m == l) goto L130;
    if (m == l - 1) {
        float rt1, rt2, c2, s2;
        slaev2f(D_(l - 1), E_(l - 1), D_(l), &rt1, &rt2, &c2, &s2);
        for (int r2 = 0; r2 < 3; ++r2) {
            float temp = ZZ(r2, l);
            ZZ(r2, l)     = c2 * temp - s2 * ZZ(r2, l - 1);
            ZZ(r2, l - 1) = s2 * temp + c2 * ZZ(r2, l - 1);
        }
        D_(l - 1) = rt1; D_(l) = rt2; E_(l - 1) = 0.0f;
        l -= 2;
        if (l >= lend) goto L90;
        goto L140;
    }
    if (jtot == nmaxit) goto L140;
    jtot++;
    g = (D_(l - 1) - p) / (2.0f * E_(l - 1));
    r = slapy2f(g, 1.0f);
    g = D_(m) - p + (E_(l - 1) / (g + f_sign(r, g)));
    s = 1.0f; c = 1.0f; p = 0.0f;
    for (int i2 = m; i2 <= l - 1; ++i2) {
        f = s * E_(i2); b = c * E_(i2);
        slartgf(g, f, &c, &s, &r);
        if (i2 != m) E_(i2 - 1) = r;
        g = D_(i2) - p;
        r = (D_(i2 + 1) - g) * s + 2.0f * c * b;
        p = s * r;
        D_(i2) = g + p;
        g = c * r - b;
        WC_(i2) = c; WS_(i2) = s;
    }
    {
        int mm = l - m + 1;
        for (int J = 1; J <= mm - 1; ++J) {
            float ct = WC_(m + J - 1), st = WS_(m + J - 1);
            for (int r2 = 0; r2 < 3; ++r2) {
                float temp = ZZ(r2, m + J);
                ZZ(r2, m + J)     = ct * temp - st * ZZ(r2, m + J - 1);
                ZZ(r2, m + J - 1) = st * temp + ct * ZZ(r2, m + J - 1);
            }
        }
    }
    D_(l) = D_(l) - p;
    E_(l - 1) = g;
    goto L90;
L130:
    D_(l) = p;
    l--;
    if (l >= lend) goto L90;
    goto L140;

L140:
    if (jtot < nmaxit) goto L10;
    goto L190;

L160: // selection sort ascending, swapping eigenvector columns
    for (int ii = 2; ii <= n; ++ii) {
        int i2 = ii - 1, k2 = i2;
        p = D_(i2);
        for (int j2 = ii; j2 <= n; ++j2)
            if (D_(j2) < p) { k2 = j2; p = D_(j2); }
        if (k2 != i2) {
            D_(k2) = D_(i2); D_(i2) = p;
            for (int r2 = 0; r2 < 3; ++r2) {
                float t = ZZ(r2, i2); ZZ(r2, i2) = ZZ(r2, k2); ZZ(r2, k2) = t;
            }
        }
    }
L190:
    // sormtr: Z := H1 * Z, H1 = I - tau*v*v^T, v = (0,1,v2)
    // (reference sger association: row2 += v2 * ((-tau)*w))
    if (tau != 0.0f) {
        for (int cf = 1; cf <= 3; ++cf) {
            float wv = ZZ(1, cf) + v2 * ZZ(2, cf);
            float tw = tau * wv;
            ZZ(1, cf) = ZZ(1, cf) - tw;
            ZZ(2, cf) = ZZ(2, cf) - v2 * tw;
        }
    }
    evals[0] = D_(1); evals[1] = D_(2); evals[2] = D_(3);
    nvec[0] = ZZ(0, 1); nvec[1] = ZZ(1, 1); nvec[2] = ZZ(2, 1);
#undef D_
#undef E_
#undef WC_
#undef WS_
#undef ZZ
}

// ---------------- packed-key top-16 machinery ----------------
// key = (float_bits(d) << 32) | idx. d >= 0 finite => IEEE bit order == numeric
// order, idx in [0, 8192) => lex (d asc, idx asc) == unsigned 64-bit ascending.
// Keys are UNIQUE (idx field). Sentinel ~0ull > any real key.

typedef unsigned long long u64;

__device__ __forceinline__ u64 packKey(float d, int j) {
    return ((u64)__float_as_uint(d) << 32) | (unsigned int)j;
}

__device__ __forceinline__ u64 shflxor_u64(u64 v, int s) {
    unsigned int lo = (unsigned int)v;
    unsigned int hi = (unsigned int)(v >> 32);
    lo = __shfl_xor(lo, s);
    hi = __shfl_xor(hi, s);
    return ((u64)hi << 32) | lo;
}

// Force values into ARCHITECTURAL VGPRs ("v" class). Empty asm: emits zero
// instructions when already in VGPRs; forbids AGPR residence at this point.
#define PIN16(a) asm volatile("" \
    : "+v"(a[0]), "+v"(a[1]), "+v"(a[2]), "+v"(a[3]), \
      "+v"(a[4]), "+v"(a[5]), "+v"(a[6]), "+v"(a[7]), \
      "+v"(a[8]), "+v"(a[9]), "+v"(a[10]), "+v"(a[11]), \
      "+v"(a[12]), "+v"(a[13]), "+v"(a[14]), "+v"(a[15]))
#define PIN8(a) asm volatile("" \
    : "+v"(a[0]), "+v"(a[1]), "+v"(a[2]), "+v"(a[3]), \
      "+v"(a[4]), "+v"(a[5]), "+v"(a[6]), "+v"(a[7]))

// Branchless ascending compare-exchange.
__device__ __forceinline__ void csw(u64& a, u64& b) {
    bool sw = b < a;
    u64 t = sw ? b : a;
    b = sw ? a : b;
    a = t;
}

// Bitonic-merge cleanup for a 16-element bitonic sequence (ascending).
__device__ __forceinline__ void bitonic16(u64 (&bd)[16]) {
#pragma unroll
    for (int d = 8; d >= 1; d >>= 1) {
#pragma unroll
        for (int k = 0; k < 16; ++k) {
            if ((k & d) == 0) csw(bd[k], bd[k + d]);
        }
    }
}

// Batcher odd-even mergesort of 8 (19 ascending comparators).
__device__ __forceinline__ void sort8(u64 (&v)[8]) {
    csw(v[0], v[1]); csw(v[2], v[3]); csw(v[0], v[2]); csw(v[1], v[3]); csw(v[1], v[2]);
    csw(v[4], v[5]); csw(v[6], v[7]); csw(v[4], v[6]); csw(v[5], v[7]); csw(v[5], v[6]);
    csw(v[0], v[4]); csw(v[1], v[5]); csw(v[2], v[6]); csw(v[3], v[7]);
    csw(v[2], v[4]); csw(v[3], v[5]);
    csw(v[1], v[2]); csw(v[3], v[4]); csw(v[5], v[6]);
}

// Merge a SORTED-8 batch into a SORTED-16 list, keeping the 16 smallest.
// Bitonic halver with sentinel padding: bd[8+j] = min(bd[8+j], key[7-j])
// yields the exact bottom-16 of the union and is bitonic; bitonic16 sorts it.
__device__ __forceinline__ void merge8into16(u64 (&bd)[16], u64 (&key)[8]) {
#pragma unroll
    for (int j = 0; j < 8; ++j) {
        u64 o = key[7 - j];
        bd[8 + j] = (o < bd[8 + j]) ? o : bd[8 + j];
    }
    bitonic16(bd);
}

// Snapshot-free tree-merge step across lane^s partners. Lanes with
// sub % (2s) == 0 merge their partner's (frozen) sorted list into their own:
// Batcher halver L[k] = min(A[k], B[15-k]) (exact top-16 of the union, bitonic)
// followed by the bitonic cleanup. Exact for globally-distinct real keys.
// After steps s = 1..G/2, lane sub==0 holds the group's top-16.
__device__ __forceinline__ void mergeTree(u64 (&bd)[16], int sub, int s) {
    bool active = ((sub & (2 * s - 1)) == 0);
#pragma unroll
    for (int k = 0; k < 16; ++k) {
        u64 od = shflxor_u64(bd[15 - k], s);   // partner is frozen => safe, no snapshot
        bool take = active && (od < bd[k]);
        bd[k] = take ? od : bd[k];
    }
    bitonic16(bd);
}

// ---------------- kernels ----------------

// Fused independent pre-pass:
//   blocks [0, NQ/8):        nearest-GT -> idealW (32 threads/query)
//   blocks [NQ/8, +NQ/32):   per-patch 16-NN -> idxP (8 threads/query, network)
// Block-uniform branch; both paths use the same 4 KB LDS tile.
__global__ void __launch_bounds__(256, 4) kAux(
        const float* __restrict__ pts, const float* __restrict__ gtP,
        const float* __restrict__ gtN, float* __restrict__ idealW,
        int* __restrict__ idxP) {
#pragma clang fp contract(off)
    __shared__ float4 shb[256];
    int tid = threadIdx.x;
    if (blockIdx.x < NQ / 8) {
        // ---- nearest ground-truth point -> ideal normal ----
        int sub = tid & 31;
        int qL = tid >> 5;
        int qrow = blockIdx.x * 8 + qL;
        int b = qrow >> 13, bbase = b << 13;
        float px = pts[qrow * 3 + 0], py = pts[qrow * 3 + 1], pz = pts[qrow * 3 + 2];
        float dm = FLT_MAX; int im = INT_MAX;
        for (int t = 0; t < NPTS / 256; ++t) {
            int crow = bbase + t * 256 + tid;
            shb[tid] = make_float4(gtP[crow * 3 + 0], gtP[crow * 3 + 1], gtP[crow * 3 + 2], 0.f);
            __syncthreads();
#pragma unroll
            for (int i = 0; i < 8; ++i) {
                int cj = sub + 32 * i;
                float4 cpt = shb[cj];
                float dx = px - cpt.x;
                float dy = py - cpt.y;
                float dz = pz - cpt.z;
                float d = sqrtf(dx * dx + dy * dy + dz * dz);
                int j = t * 256 + cj;
                bool take = (d < dm) || (d == dm && j < im);
                dm = take ? d : dm;
                im = take ? j : im;
            }
            __syncthreads();
        }
        // lex-min butterfly within the 32-lane query group (branchless)
#pragma unroll
        for (int s = 1; s < 32; s <<= 1) {
            float od = __shfl_xor(dm, s);
            int   oi = __shfl_xor(im, s);
            bool take = (od < dm) || (od == dm && oi < im);
            dm = take ? od : dm;
            im = take ? oi : im;
        }
        if (sub == 0) {
            int src = bbase + im;
            idealW[qrow * 3 + 0] = gtN[src * 3 + 0];
            idealW[qrow * 3 + 1] = gtN[src * 3 + 1];
            idealW[qrow * 3 + 2] = gtN[src * 3 + 2];
        }
    } else {
        // ---- per-patch 16-NN (no mask), 8 threads/query, batched network ----
        int pb = blockIdx.x - NQ / 8;
        int sub = tid & 7;
        int qL = tid >> 3;
        int qrow = pb * 32 + qL;
        int pbase = ((pb * 32) >> 8) << 8;   // uniform per block (32 queries/patch-slice)
        int crow = pbase + tid;
        shb[tid] = make_float4(pts[crow * 3 + 0], pts[crow * 3 + 1], pts[crow * 3 + 2], 0.f);
        __syncthreads();
        float px = pts[qrow * 3 + 0], py = pts[qrow * 3 + 1], pz = pts[qrow * 3 + 2];
        u64 bd[16];
#pragma unroll
        for (int k = 0; k < 16; ++k) bd[k] = ~0ull;
        for (int batch = 0; batch < 4; ++batch) {
            u64 key[8];
#pragma unroll
            for (int i = 0; i < 8; ++i) {
                int cj = sub + 64 * batch + 8 * i;
                float4 cpt = shb[cj];
                float dx = cpt.x - px;
                float dy = cpt.y - py;
                float dz = cpt.z - pz;
                float d = sqrtf(dx * dx + dy * dy + dz * dz);
                key[i] = packKey(d, cj);
            }
            sort8(key);
            merge8into16(bd, key);
        }
        mergeTree(bd, sub, 1);
        mergeTree(bd, sub, 2);
        mergeTree(bd, sub, 4);
        if (sub == 0) {
#pragma unroll
            for (int k = 0; k < 16; ++k)
                idxP[qrow * KNN + k] = pbase + (int)(bd[k] & 0xffffffffu);
        }
    }
}

// Masked global 16-NN, batched-network selection. 32 threads/query; float4 LDS
// tiles. Per tile: (1) compute 8 keys branch-free (full ILP); (2) sort8 via
// Batcher's 19-comparator network; (3) bitonic-halver merge into the sorted
// per-thread top-16 (+32-cswap cleanup). Top-16 of a multiset is batch-order
// independent => per-thread result identical to sequential insertion => final
// tree-merge output bit-identical to prior rounds. No gates, no queues.
// PIN16/PIN8: r12/r13 builds allocated only 40 arch VGPRs (< the ~60 live
// values), holding bd/key in AGPRs with v_accvgpr shuttles (~3x VALU bloat).
// The empty-asm "v"-class pins force bd/key into arch VGPRs per tile.
// Mask dot replicates the reference einsum GEMM accumulation: FMA, k-asc.
__global__ void __launch_bounds__(256, 2) kGlobalKNN(
        const float* __restrict__ pts, const float* __restrict__ idealW,
        int* __restrict__ idxG) {
#pragma clang fp contract(off)
    __shared__ float4 sp[256];
    __shared__ float4 si[256];
    int tid = threadIdx.x;
    int sub = tid & 31;
    int qL = tid >> 5;
    int qrow = blockIdx.x * 8 + qL;
    int b = qrow >> 13, bbase = b << 13;
    float px = pts[qrow * 3 + 0], py = pts[qrow * 3 + 1], pz = pts[qrow * 3 + 2];
    float ix = idealW[qrow * 3 + 0], iy = idealW[qrow * 3 + 1], iz = idealW[qrow * 3 + 2];
    const float cthr = -3.6199900765e-06f;   // cos(float32(1.5708)), correctly rounded
    u64 bd[16];
#pragma unroll
    for (int k = 0; k < 16; ++k) bd[k] = ~0ull;
    PIN16(bd);
    for (int t = 0; t < NPTS / 256; ++t) {
        int crow = bbase + t * 256 + tid;
        sp[tid] = make_float4(pts[crow * 3 + 0], pts[crow * 3 + 1], pts[crow * 3 + 2], 0.f);
        si[tid] = make_float4(idealW[crow * 3 + 0], idealW[crow * 3 + 1], idealW[crow * 3 + 2], 0.f);
        __syncthreads();
        // phase 1: all 8 keys, branch-free
        u64 key[8];
#pragma unroll
        for (int i = 0; i < 8; ++i) {
            int cj = sub + 32 * i;
            float4 cpt = sp[cj];
            float4 cnr = si[cj];
            float dx = cpt.x - px;
            float dy = cpt.y - py;
            float dz = cpt.z - pz;
            float d = sqrtf(dx * dx + dy * dy + dz * dz);
            // GEMM-style: fma(i2,s2, fma(i1,s1, i0*s0))
            float dot = fmaf(iz, cnr.z, fmaf(iy, cnr.y, ix * cnr.x));
            if (dot <= cthr) d = 1.0e8f;     // _USRINF, exactly representable
            key[i] = packKey(d, t * 256 + cj);
        }
        // pin bd/key into arch VGPRs before the comparator network
        PIN8(key);
        PIN16(bd);
        // phase 2: batched exact selection
        sort8(key);
        merge8into16(bd, key);
        __syncthreads();
    }
    // tree-merge the 32 per-thread sorted lists of this query (one wave = 2 queries)
    PIN16(bd);
    mergeTree(bd, sub, 1);
    mergeTree(bd, sub, 2);
    mergeTree(bd, sub, 4);
    mergeTree(bd, sub, 8);
    mergeTree(bd, sub, 16);
    if (sub == 0) {
#pragma unroll
        for (int k = 0; k < 16; ++k)
            idxG[qrow * KNN + k] = bbase + (int)(bd[k] & 0xffffffffu);
    }
}

// Covariance (GEMM-style FMA accumulation, k-ascending) + LAPACK-faithful eigh.
// 64-thread blocks -> 512 blocks spread over all 256 CUs (latency-bound kernel).
__global__ void __launch_bounds__(64) kEigen(
        const float* __restrict__ pts,
        const int* __restrict__ idxG, const int* __restrict__ idxP,
        float* __restrict__ outNormG, float* __restrict__ svG,
        float* __restrict__ normP, float* __restrict__ svP) {
#pragma clang fp contract(off)
    __shared__ float Wall[64 * 27];
    int tid = threadIdx.x;
    int t = blockIdx.x * 64 + tid;
    int isG = (t < NQ) ? 1 : 0;
    int q = isG ? t : (t - NQ);
    const int* idxArr = isG ? idxG : idxP;
    float cx = pts[q * 3 + 0], cy = pts[q * 3 + 1], cz = pts[q * 3 + 2];
    float c00 = 0.f, c10 = 0.f, c11 = 0.f, c20 = 0.f, c21 = 0.f, c22 = 0.f;
    for (int k = 0; k < KNN; ++k) {
        int nb = idxArr[q * KNN + k];
        float vx = pts[nb * 3 + 0] - cx;
        float vy = pts[nb * 3 + 1] - cy;
        float vz = pts[nb * 3 + 2] - cz;
        c00 = fmaf(vx, vx, c00);
        c10 = fmaf(vy, vx, c10);
        c11 = fmaf(vy, vy, c11);
        c20 = fmaf(vz, vx, c20);
        c21 = fmaf(vz, vy, c21);
        c22 = fmaf(vz, vz, c22);
    }
    float cov[6] = {c00, c10, c11, c20, c21, c22};
    float evals[3], nv[3];
    eigh3_lapack(cov, &Wall[tid * 27], evals, nv);
    float sv = evals[0] / ((evals[0] + evals[1]) + evals[2]);
    if (isG) {
        outNormG[q * 3 + 0] = nv[0];
        outNormG[q * 3 + 1] = nv[1];
        outNormG[q * 3 + 2] = nv[2];
        svG[q] = sv;
    } else {
        normP[q * 3 + 0] = nv[0];
        normP[q * 3 + 1] = nv[1];
        normP[q * 3 + 2] = nv[2];
        svP[q] = sv;
    }
}

// Final scalar losses.
__global__ void __launch_bounds__(256) kLoss(
        const float* __restrict__ normP, const float* __restrict__ svP,
        const float* __restrict__ svG, const float* __restrict__ normG,
        float* __restrict__ out) {
#pragma clang fp contract(off)
    __shared__ double sA[256];
    __shared__ double sB[256];
    int tid = threadIdx.x;
    double accN = 0.0, accS = 0.0;
    for (int q = tid; q < NQ; q += 256) {
        float ax = fabsf(normP[q * 3 + 0]) - fabsf(normG[q * 3 + 0]);
        float ay = fabsf(normP[q * 3 + 1]) - fabsf(normG[q * 3 + 1]);
        float az = fabsf(normP[q * 3 + 2]) - fabsf(normG[q * 3 + 2]);
        accN += (double)sqrtf(ax * ax + ay * ay + az * az);
        float ds = svP[q] - svG[q];
        accS += (double)(ds * ds);
    }
    sA[tid] = accN; sB[tid] = accS;
    __syncthreads();
    for (int s2 = 128; s2 > 0; s2 >>= 1) {
        if (tid < s2) { sA[tid] += sA[tid + s2]; sB[tid] += sB[tid + s2]; }
        __syncthreads();
    }
    if (tid == 0) {
        out[0] = (float)(sA[0] / (double)NQ);   // * W_NORMAL (=1)
        out[1] = (float)(sB[0] / (double)NQ);   // * W_SURFVAR (=1)
    }
}

extern "C" void kernel_launch(void* const* d_in, const int* in_sizes, int n_in,
                              void* d_out, int out_size, void* d_ws, size_t ws_size,
                              hipStream_t stream) {
    const float* pts = (const float*)d_in[0];
    const float* gtP = (const float*)d_in[1];
    const float* gtN = (const float*)d_in[2];
    float* out = (float*)d_out;
    float* ws = (float*)d_ws;

    float* idealW = ws;                        // NQ*3 floats
    int* idxG = (int*)(ws + NQ * 3);           // NQ*16 ints
    int* idxP = idxG + NQ * KNN;               // NQ*16 ints
    float* normP = (float*)(idxP + NQ * KNN);  // NQ*3 floats
    float* svG = normP + NQ * 3;               // NQ floats
    float* svP = svG + NQ;                     // NQ floats
    float* outNormG = out + 2;

    kAux<<<dim3(NQ / 8 + NQ / 32), dim3(256), 0, stream>>>(pts, gtP, gtN, idealW, idxP);
    kGlobalKNN<<<dim3(NQ / 8), dim3(256), 0, stream>>>(pts, idealW, idxG);
    kEigen<<<dim3(2 * NQ / 64), dim3(64), 0, stream>>>(pts, idxG, idxP,
                                                       outNormG, svG, normP, svP);
    kLoss<<<dim3(1), dim3(256), 0, stream>>>(normP, svP, svG, outNormG, out);
}

// Round 15
// 402.870 us; speedup vs baseline: 1.0358x; 1.0358x over previous
//
#include <hip/hip_runtime.h>
#include <hip/hip_bf16.h>
#include <float.h>
#include <limits.h>

#define NPTS 8192
#define NB 2
#define NQ (NB * NPTS)   // 16384
#define KNN 16
#define NPATCHES 64      // B * NUM_PATCHES, 256 points each

// ---------------- LAPACK float32 helpers (faithful ports) ----------------

__device__ __forceinline__ float f_sign(float a, float b) {
    float aa = fabsf(a);
    return (b >= 0.0f) ? aa : -aa;
}

__device__ __forceinline__ float slapy2f(float x, float y) {
#pragma clang fp contract(off)
    float xa = fabsf(x), ya = fabsf(y);
    float w = fmaxf(xa, ya), z = fminf(xa, ya);
    if (z == 0.0f) return w;
    float q = z / w;
    return w * sqrtf(1.0f + q * q);
}

// LAPACK >= 3.10 slartg convention (r carries sign of f)
__device__ __forceinline__ void slartgf(float f, float g, float* cs, float* sn, float* r) {
#pragma clang fp contract(off)
    if (g == 0.0f) { *cs = 1.0f; *sn = 0.0f; *r = f; }
    else if (f == 0.0f) { *cs = 0.0f; *sn = (g >= 0.0f) ? 1.0f : -1.0f; *r = fabsf(g); }
    else {
        float d = sqrtf(f * f + g * g);
        *cs = fabsf(f) / d;
        float rr = f_sign(d, f);
        *sn = g / rr;
        *r = rr;
    }
}

__device__ void slaev2f(float a, float b, float c, float* rt1, float* rt2,
                        float* cs1, float* sn1) {
#pragma clang fp contract(off)
    float sm = a + c, df = a - c;
    float adf = fabsf(df);
    float tb = b + b;
    float ab = fabsf(tb);
    float acmx, acmn;
    if (fabsf(a) > fabsf(c)) { acmx = a; acmn = c; } else { acmx = c; acmn = a; }
    float rt;
    if (adf > ab)      { float q = ab / adf; rt = adf * sqrtf(1.0f + q * q); }
    else if (adf < ab) { float q = adf / ab; rt = ab * sqrtf(1.0f + q * q); }
    else               { rt = ab * sqrtf(2.0f); }
    int sgn1;
    if (sm < 0.0f) {
        *rt1 = 0.5f * (sm - rt); sgn1 = -1;
        *rt2 = (acmx / *rt1) * acmn - (b / *rt1) * b;
    } else if (sm > 0.0f) {
        *rt1 = 0.5f * (sm + rt); sgn1 = 1;
        *rt2 = (acmx / *rt1) * acmn - (b / *rt1) * b;
    } else {
        *rt1 = 0.5f * rt; *rt2 = -0.5f * rt; sgn1 = 1;
    }
    float cs; int sgn2;
    if (df >= 0.0f) { cs = df + rt; sgn2 = 1; } else { cs = df - rt; sgn2 = -1; }
    float acs = fabsf(cs);
    if (acs > ab) {
        float ct = -tb / cs;
        *sn1 = 1.0f / sqrtf(1.0f + ct * ct);
        *cs1 = ct * (*sn1);
    } else {
        if (ab == 0.0f) { *cs1 = 1.0f; *sn1 = 0.0f; }
        else {
            float tn = -cs / tb;
            *cs1 = 1.0f / sqrtf(1.0f + tn * tn);
            *sn1 = tn * (*cs1);
        }
    }
    if (sgn1 == sgn2) { float tn = *cs1; *cs1 = -(*sn1); *sn1 = tn; }
}

// Faithful ssyevd(jobz='V', uplo='L') for 3x3: ssytd2 + ssteqr('I') + sormtr.
// cov = [c00, c10, c11, c20, c21, c22] (lower triangle).
// W: 27-float per-thread scratch (LDS). evals ascending; nvec = eigvec col 0.
__device__ void eigh3_lapack(const float cov[6], float* W, float evals[3], float nvec[3]) {
#pragma clang fp contract(off)
    const float eps = 5.9604644775390625e-08f;   // slamch('E') fp32
    const float eps2 = eps * eps;
    const float safmin = 1.1754943508222875e-38f;
#define D_(i)  W[(i)]
#define E_(i)  W[4 + (i)]
#define WC_(i) W[8 + (i)]
#define WS_(i) W[12 + (i)]
#define ZZ(r, cf) W[16 + ((cf) - 1) * 3 + (r)]
    float a00 = cov[0], a10 = cov[1], a11 = cov[2], a20 = cov[3], a21 = cov[4], a22 = cov[5];

    // ---- ssytd2 (lower), n=3: one reflector annihilating A(3,1)
    float tau, v2, beta;
    {
        float alpha = a10;
        float xnorm = fabsf(a20);
        if (xnorm == 0.0f) { tau = 0.0f; v2 = 0.0f; beta = alpha; }
        else {
            beta = -f_sign(slapy2f(alpha, xnorm), alpha);
            tau = (beta - alpha) / beta;
            v2 = a20 * (1.0f / (alpha - beta));
            // ssymv (reference BLAS association): p0 = tau*a11 + tau*(a21*v2)
            float p0 = tau * a11 + tau * (a21 * v2);
            float p1 = tau * a21 + (tau * v2) * a22;
            float al = -0.5f * tau * (p0 + p1 * v2);
            float w0 = p0 + al;
            float w1 = p1 + al * v2;
            a11 = (a11 - w0) - w0;
            a21 = (a21 - v2 * w0) - w1;
            a22 = (a22 - v2 * w1) - w1 * v2;
        }
    }
    D_(1) = a00; D_(2) = a11; D_(3) = a22;
    E_(1) = beta; E_(2) = a21;
    for (int cf = 1; cf <= 3; ++cf)
        for (int r0 = 0; r0 < 3; ++r0)
            ZZ(r0, cf) = (r0 == cf - 1) ? 1.0f : 0.0f;

    // ---- ssteqr('I', n=3)
    const int n = 3;
    int nmaxit = n * 30, jtot = 0, l1 = 1;
    int l, m, lsv, lend, lendsv;
    float p, g, r, c, s, f, b;

L10:
    if (l1 > n) goto L160;
    if (l1 > 1) E_(l1 - 1) = 0.0f;
    m = n;
    if (l1 <= n - 1) {
        for (int mi = l1; mi <= n - 1; ++mi) {
            float tst = fabsf(E_(mi));
            if (tst == 0.0f) { m = mi; goto L30; }
            if (tst <= (sqrtf(fabsf(D_(mi))) * sqrtf(fabsf(D_(mi + 1)))) * eps) {
                E_(mi) = 0.0f; m = mi; goto L30;
            }
        }
        m = n;
    }
L30:
    l = l1; lsv = l; lend = m; lendsv = lend; l1 = m + 1;
    if (lend == l) goto L10;
    {
        float anorm = fabsf(D_(lend));
        for (int i2 = l; i2 <= lend - 1; ++i2) {
            anorm = fmaxf(anorm, fabsf(D_(i2)));
            anorm = fmaxf(anorm, fabsf(E_(i2)));
        }
        if (anorm == 0.0f) goto L10;
        // scaling branch omitted: cov magnitudes are O(1e-3..1e2), far inside [ssfmin, ssfmax]
    }
    if (fabsf(D_(lend)) < fabsf(D_(l))) { lend = lsv; l = lendsv; }
    if (lend > l) goto L40;
    goto L90;

    // ---------- QL iteration ----------
L40:
    if (l != lend) {
        m = lend;
        for (int mi = l; mi <= lend - 1; ++mi) {
            float tst = fabsf(E_(mi)); tst = tst * tst;
            if (tst <= (eps2 * fabsf(D_(mi))) * fabsf(D_(mi + 1)) + safmin) { m = mi; goto L60; }
        }
    } else { m = lend; }
L60:
    if (m < lend) E_(m) = 0.0f;
    p = D_(l);
    if (m == l) goto L80;
    if (m == l + 1) {
        float rt1, rt2, c2, s2;
        slaev2f(D_(l), E_(l), D_(l + 1), &rt1, &rt2, &c2, &s2);
        for (int r2 = 0; r2 < 3; ++r2) {
            float temp = ZZ(r2, l + 1);
            ZZ(r2, l + 1) = c2 * temp - s2 * ZZ(r2, l);
            ZZ(r2, l)     = s2 * temp + c2 * ZZ(r2, l);
        }
        D_(l) = rt1; D_(l + 1) = rt2; E_(l) = 0.0f;
        l += 2;
        if (l <= lend) goto L40;
        goto L140;
    }
    if (jtot == nmaxit) goto L140;
    jtot++;
    g = (D_(l + 1) - p) / (2.0f * E_(l));
    r = slapy2f(g, 1.0f);
    g = D_(m) - p + (E_(l) / (g + f_sign(r, g)));
    s = 1.0f; c = 1.0f; p = 0.0f;
    for (int i2 = m - 1; i2 >= l; --i2) {
        f = s * E_(i2); b = c * E_(i2);
        slartgf(g, f, &c, &s, &r);
        if (i2 != m - 1) E_(i2 + 1) = r;
        g = D_(i2 + 1) - p;
        r = (D_(i2) - g) * s + 2.0f * c * b;
        p = s * r;
        D_(i2 + 1) = g + p;
        g = c * r - b;
        WC_(i2) = c; WS_(i2) = -s;
    }
    {
        int mm = m - l + 1;
        for (int J = mm - 1; J >= 1; --J) {
            float ct = WC_(l + J - 1), st = WS_(l + J - 1);
            for (int r2 = 0; r2 < 3; ++r2) {
                float temp = ZZ(r2, l + J);
                ZZ(r2, l + J)     = ct * temp - st * ZZ(r2, l + J - 1);
                ZZ(r2, l + J - 1) = st * temp + ct * ZZ(r2, l + J - 1);
            }
        }
    }
    D_(l) = D_(l) - p;
    E_(l) = g;
    goto L40;
L80:
    D_(l) = p;
    l++;
    if (l <= lend) goto L40;
    goto L140;

    // ---------- QR iteration ----------
L90:
    if (l != lend) {
        m = lend;
        for (int mi = l; mi >= lend + 1; --mi) {
            float tst = fabsf(E_(mi - 1)); tst = tst * tst;
            if (tst <= (eps2 * fabsf(D_(mi))) * fabsf(D_(mi - 1)) + safmin) { m = mi; goto L110; }
        }
    } else { m = lend; }
L110:
    if (m > lend) E_(m - 1) = 0.0f;
    p = D_(l);
    if (m == l) goto L130;
    if (m == l - 1) {
        float rt1, rt2, c2, s2;
        slaev2f(D_(l - 1), E_(l - 1), D_(l), &rt1, &rt2, &c2, &s2);
        for (int r2 = 0; r2 < 3; ++r2) {
            float temp = ZZ(r2, l);
            ZZ(r2, l)     = c2 * temp - s2 * ZZ(r2, l - 1);
            ZZ(r2, l - 1) = s2 * temp + c2 * ZZ(r2, l - 1);
        }
        D_(l - 1) = rt1; D_(l) = rt2; E_(l - 1) = 0.0f;
        l -= 2;
        if (l >= lend) goto L90;
        goto L140;
    }
    if (jtot == nmaxit) goto L140;
    jtot++;
    g = (D_(l - 1) - p) / (2.0f * E_(l - 1));
    r = slapy2f(g, 1.0f);
    g = D_(m) - p + (E_(l - 1) / (g + f_sign(r, g)));
    s = 1.0f; c = 1.0f; p = 0.0f;
    for (int i2 = m; i2 <= l - 1; ++i2) {
        f = s * E_(i2); b = c * E_(i2);
        slartgf(g, f, &c, &s, &r);
        if (i2 != m) E_(i2 - 1) = r;
        g = D_(i2) - p;
        r = (D_(i2 + 1) - g) * s + 2.0f * c * b;
        p = s * r;
        D_(i2) = g + p;
        g = c * r - b;
        WC_(i2) = c; WS_(i2) = s;
    }
    {
        int mm = l - m + 1;
        for (int J = 1; J <= mm - 1; ++J) {
            float ct = WC_(m + J - 1), st = WS_(m + J - 1);
            for (int r2 = 0; r2 < 3; ++r2) {
                float temp = ZZ(r2, m + J);
                ZZ(r2, m + J)     = ct * temp - st * ZZ(r2, m + J - 1);
                ZZ(r2, m + J - 1) = st * temp + ct * ZZ(r2, m + J - 1);
            }
        }
    }
    D_(l) = D_(l) - p;
    E_(l - 1) = g;
    goto L90;
L130:
    D_(l) = p;
    l--;
    if (l >= lend) goto L90;
    goto L140;

L140:
    if (jtot < nmaxit) goto L10;
    goto L190;

L160: // selection sort ascending, swapping eigenvector columns
    for (int ii = 2; ii <= n; ++ii) {
        int i2 = ii - 1, k2 = i2;
        p = D_(i2);
        for (int j2 = ii; j2 <= n; ++j2)
            if (D_(j2) < p) { k2 = j2; p = D_(j2); }
        if (k2 != i2) {
            D_(k2) = D_(i2); D_(i2) = p;
            for (int r2 = 0; r2 < 3; ++r2) {
                float t = ZZ(r2, i2); ZZ(r2, i2) = ZZ(r2, k2); ZZ(r2, k2) = t;
            }
        }
    }
L190:
    // sormtr: Z := H1 * Z, H1 = I - tau*v*v^T, v = (0,1,v2)
    // (reference sger association: row2 += v2 * ((-tau)*w))
    if (tau != 0.0f) {
        for (int cf = 1; cf <= 3; ++cf) {
            float wv = ZZ(1, cf) + v2 * ZZ(2, cf);
            float tw = tau * wv;
            ZZ(1, cf) = ZZ(1, cf) - tw;
            ZZ(2, cf) = ZZ(2, cf) - v2 * tw;
        }
    }
    evals[0] = D_(1); evals[1] = D_(2); evals[2] = D_(3);
    nvec[0] = ZZ(0, 1); nvec[1] = ZZ(1, 1); nvec[2] = ZZ(2, 1);
#undef D_
#undef E_
#undef WC_
#undef WS_
#undef ZZ
}

// ---------------- packed-key top-16 machinery ----------------
// key = (float_bits(d) << 32) | idx. d >= 0 finite => IEEE bit order == numeric
// order, idx in [0, 8192) => lex (d asc, idx asc) == unsigned 64-bit ascending.
// Keys are UNIQUE (idx field). Sentinel ~0ull > any real key.

typedef unsigned long long u64;

__device__ __forceinline__ u64 packKey(float d, int j) {
    return ((u64)__float_as_uint(d) << 32) | (unsigned int)j;
}

__device__ __forceinline__ u64 shflxor_u64(u64 v, int s) {
    unsigned int lo = (unsigned int)v;
    unsigned int hi = (unsigned int)(v >> 32);
    lo = __shfl_xor(lo, s);
    hi = __shfl_xor(hi, s);
    return ((u64)hi << 32) | lo;
}

// Branchless ascending compare-exchange.
__device__ __forceinline__ void csw(u64& a, u64& b) {
    bool sw = b < a;
    u64 t = sw ? b : a;
    b = sw ? a : b;
    a = t;
}

// Sorted-ascending insert (registers only; static indexing).
__device__ __forceinline__ void insert16(u64 (&bd)[16], u64 key) {
    if (key >= bd[15]) return;
    bd[15] = key;
#pragma unroll
    for (int k = 15; k >= 1; --k) {
        if (bd[k] < bd[k - 1]) { u64 t = bd[k]; bd[k] = bd[k - 1]; bd[k - 1] = t; }
    }
}

// Bitonic-merge cleanup for a 16-element bitonic sequence (ascending).
__device__ __forceinline__ void bitonic16(u64 (&bd)[16]) {
#pragma unroll
    for (int d = 8; d >= 1; d >>= 1) {
#pragma unroll
        for (int k = 0; k < 16; ++k) {
            if ((k & d) == 0) csw(bd[k], bd[k + d]);
        }
    }
}

// Batcher odd-even mergesort of 8 (19 ascending comparators).
__device__ __forceinline__ void sort8(u64 (&v)[8]) {
    csw(v[0], v[1]); csw(v[2], v[3]); csw(v[0], v[2]); csw(v[1], v[3]); csw(v[1], v[2]);
    csw(v[4], v[5]); csw(v[6], v[7]); csw(v[4], v[6]); csw(v[5], v[7]); csw(v[5], v[6]);
    csw(v[0], v[4]); csw(v[1], v[5]); csw(v[2], v[6]); csw(v[3], v[7]);
    csw(v[2], v[4]); csw(v[3], v[5]);
    csw(v[1], v[2]); csw(v[3], v[4]); csw(v[5], v[6]);
}

// Merge a SORTED-8 batch into a SORTED-16 list, keeping the 16 smallest.
// Bitonic halver with sentinel padding: bd[8+j] = min(bd[8+j], key[7-j])
// yields the exact bottom-16 of the union and is bitonic; bitonic16 sorts it.
__device__ __forceinline__ void merge8into16(u64 (&bd)[16], u64 (&key)[8]) {
#pragma unroll
    for (int j = 0; j < 8; ++j) {
        u64 o = key[7 - j];
        bd[8 + j] = (o < bd[8 + j]) ? o : bd[8 + j];
    }
    bitonic16(bd);
}

// Snapshot-free tree-merge step across lane^s partners. Lanes with
// sub % (2s) == 0 merge their partner's (frozen) sorted list into their own:
// Batcher halver L[k] = min(A[k], B[15-k]) (exact top-16 of the union, bitonic)
// followed by the bitonic cleanup. Exact for globally-distinct real keys.
// After steps s = 1..G/2, lane sub==0 holds the group's top-16.
__device__ __forceinline__ void mergeTree(u64 (&bd)[16], int sub, int s) {
    bool active = ((sub & (2 * s - 1)) == 0);
#pragma unroll
    for (int k = 0; k < 16; ++k) {
        u64 od = shflxor_u64(bd[15 - k], s);   // partner is frozen => safe, no snapshot
        bool take = active && (od < bd[k]);
        bd[k] = take ? od : bd[k];
    }
    bitonic16(bd);
}

// ---------------- kernels ----------------

// Fused independent pre-pass:
//   blocks [0, NQ/8):        nearest-GT -> idealW (32 threads/query)
//   blocks [NQ/8, +NQ/32):   per-patch 16-NN -> idxP (8 threads/query, network)
// Block-uniform branch; both paths use the same 4 KB LDS tile.
__global__ void __launch_bounds__(256, 4) kAux(
        const float* __restrict__ pts, const float* __restrict__ gtP,
        const float* __restrict__ gtN, float* __restrict__ idealW,
        int* __restrict__ idxP) {
#pragma clang fp contract(off)
    __shared__ float4 shb[256];
    int tid = threadIdx.x;
    if (blockIdx.x < NQ / 8) {
        // ---- nearest ground-truth point -> ideal normal ----
        int sub = tid & 31;
        int qL = tid >> 5;
        int qrow = blockIdx.x * 8 + qL;
        int b = qrow >> 13, bbase = b << 13;
        float px = pts[qrow * 3 + 0], py = pts[qrow * 3 + 1], pz = pts[qrow * 3 + 2];
        float dm = FLT_MAX; int im = INT_MAX;
        for (int t = 0; t < NPTS / 256; ++t) {
            int crow = bbase + t * 256 + tid;
            shb[tid] = make_float4(gtP[crow * 3 + 0], gtP[crow * 3 + 1], gtP[crow * 3 + 2], 0.f);
            __syncthreads();
#pragma unroll
            for (int i = 0; i < 8; ++i) {
                int cj = sub + 32 * i;
                float4 cpt = shb[cj];
                float dx = px - cpt.x;
                float dy = py - cpt.y;
                float dz = pz - cpt.z;
                float d = sqrtf(dx * dx + dy * dy + dz * dz);
                int j = t * 256 + cj;
                bool take = (d < dm) || (d == dm && j < im);
                dm = take ? d : dm;
                im = take ? j : im;
            }
            __syncthreads();
        }
        // lex-min butterfly within the 32-lane query group (branchless)
#pragma unroll
        for (int s = 1; s < 32; s <<= 1) {
            float od = __shfl_xor(dm, s);
            int   oi = __shfl_xor(im, s);
            bool take = (od < dm) || (od == dm && oi < im);
            dm = take ? od : dm;
            im = take ? oi : im;
        }
        if (sub == 0) {
            int src = bbase + im;
            idealW[qrow * 3 + 0] = gtN[src * 3 + 0];
            idealW[qrow * 3 + 1] = gtN[src * 3 + 1];
            idealW[qrow * 3 + 2] = gtN[src * 3 + 2];
        }
    } else {
        // ---- per-patch 16-NN (no mask), 8 threads/query, batched network ----
        int pb = blockIdx.x - NQ / 8;
        int sub = tid & 7;
        int qL = tid >> 3;
        int qrow = pb * 32 + qL;
        int pbase = ((pb * 32) >> 8) << 8;   // uniform per block (32 queries/patch-slice)
        int crow = pbase + tid;
        shb[tid] = make_float4(pts[crow * 3 + 0], pts[crow * 3 + 1], pts[crow * 3 + 2], 0.f);
        __syncthreads();
        float px = pts[qrow * 3 + 0], py = pts[qrow * 3 + 1], pz = pts[qrow * 3 + 2];
        u64 bd[16];
#pragma unroll
        for (int k = 0; k < 16; ++k) bd[k] = ~0ull;
        for (int batch = 0; batch < 4; ++batch) {
            u64 key[8];
#pragma unroll
            for (int i = 0; i < 8; ++i) {
                int cj = sub + 64 * batch + 8 * i;
                float4 cpt = shb[cj];
                float dx = cpt.x - px;
                float dy = cpt.y - py;
                float dz = cpt.z - pz;
                float d = sqrtf(dx * dx + dy * dy + dz * dz);
                key[i] = packKey(d, cj);
            }
            sort8(key);
            merge8into16(bd, key);
        }
        mergeTree(bd, sub, 1);
        mergeTree(bd, sub, 2);
        mergeTree(bd, sub, 4);
        if (sub == 0) {
#pragma unroll
            for (int k = 0; k < 16; ++k)
                idxP[qrow * KNN + k] = pbase + (int)(bd[k] & 0xffffffffu);
        }
    }
}

// Masked global 16-NN, batched-network selection. 32 threads/query; float4 LDS
// tiles. Per tile: (1) compute 8 keys branch-free (full ILP); (2) sort8 via
// Batcher's 19-comparator network; (3) bitonic-halver merge into the sorted
// per-thread top-16 (+32-cswap cleanup). Top-16 of a multiset is batch-order
// independent => per-thread result identical to sequential insertion => final
// tree-merge output bit-identical to prior rounds. No gates, no queues.
// 97-98% VALUBusy at this shape: issue-bound at ~7.4 exact 64-bit
// compare-exchanges per masked pair (the selection-network floor).
// Mask dot replicates the reference einsum GEMM accumulation: FMA, k-asc.
__global__ void __launch_bounds__(256, 4) kGlobalKNN(
        const float* __restrict__ pts, const float* __restrict__ idealW,
        int* __restrict__ idxG) {
#pragma clang fp contract(off)
    __shared__ float4 sp[256];
    __shared__ float4 si[256];
    int tid = threadIdx.x;
    int sub = tid & 31;
    int qL = tid >> 5;
    int qrow = blockIdx.x * 8 + qL;
    int b = qrow >> 13, bbase = b << 13;
    float px = pts[qrow * 3 + 0], py = pts[qrow * 3 + 1], pz = pts[qrow * 3 + 2];
    float ix = idealW[qrow * 3 + 0], iy = idealW[qrow * 3 + 1], iz = idealW[qrow * 3 + 2];
    const float cthr = -3.6199900765e-06f;   // cos(float32(1.5708)), correctly rounded
    u64 bd[16];
#pragma unroll
    for (int k = 0; k < 16; ++k) bd[k] = ~0ull;
    for (int t = 0; t < NPTS / 256; ++t) {
        int crow = bbase + t * 256 + tid;
        sp[tid] = make_float4(pts[crow * 3 + 0], pts[crow * 3 + 1], pts[crow * 3 + 2], 0.f);
        si[tid] = make_float4(idealW[crow * 3 + 0], idealW[crow * 3 + 1], idealW[crow * 3 + 2], 0.f);
        __syncthreads();
        // phase 1: all 8 keys, branch-free
        u64 key[8];
#pragma unroll
        for (int i = 0; i < 8; ++i) {
            int cj = sub + 32 * i;
            float4 cpt = sp[cj];
            float4 cnr = si[cj];
            float dx = cpt.x - px;
            float dy = cpt.y - py;
            float dz = cpt.z - pz;
            float d = sqrtf(dx * dx + dy * dy + dz * dz);
            // GEMM-style: fma(i2,s2, fma(i1,s1, i0*s0))
            float dot = fmaf(iz, cnr.z, fmaf(iy, cnr.y, ix * cnr.x));
            if (dot <= cthr) d = 1.0e8f;     // _USRINF, exactly representable
            key[i] = packKey(d, t * 256 + cj);
        }
        // phase 2: batched exact selection
        sort8(key);
        merge8into16(bd, key);
        __syncthreads();
    }
    // tree-merge the 32 per-thread sorted lists of this query (one wave = 2 queries)
    mergeTree(bd, sub, 1);
    mergeTree(bd, sub, 2);
    mergeTree(bd, sub, 4);
    mergeTree(bd, sub, 8);
    mergeTree(bd, sub, 16);
    if (sub == 0) {
#pragma unroll
        for (int k = 0; k < 16; ++k)
            idxG[qrow * KNN + k] = bbase + (int)(bd[k] & 0xffffffffu);
    }
}

// Covariance (GEMM-style FMA accumulation, k-ascending) + LAPACK-faithful eigh.
// 64-thread blocks -> 512 blocks spread over all 256 CUs (latency-bound kernel).
__global__ void __launch_bounds__(64) kEigen(
        const float* __restrict__ pts,
        const int* __restrict__ idxG, const int* __restrict__ idxP,
        float* __restrict__ outNormG, float* __restrict__ svG,
        float* __restrict__ normP, float* __restrict__ svP) {
#pragma clang fp contract(off)
    __shared__ float Wall[64 * 27];
    int tid = threadIdx.x;
    int t = blockIdx.x * 64 + tid;
    int isG = (t < NQ) ? 1 : 0;
    int q = isG ? t : (t - NQ);
    const int* idxArr = isG ? idxG : idxP;
    float cx = pts[q * 3 + 0], cy = pts[q * 3 + 1], cz = pts[q * 3 + 2];
    float c00 = 0.f, c10 = 0.f, c11 = 0.f, c20 = 0.f, c21 = 0.f, c22 = 0.f;
    for (int k = 0; k < KNN; ++k) {
        int nb = idxArr[q * KNN + k];
        float vx = pts[nb * 3 + 0] - cx;
        float vy = pts[nb * 3 + 1] - cy;
        float vz = pts[nb * 3 + 2] - cz;
        c00 = fmaf(vx, vx, c00);
        c10 = fmaf(vy, vx, c10);
        c11 = fmaf(vy, vy, c11);
        c20 = fmaf(vz, vx, c20);
        c21 = fmaf(vz, vy, c21);
        c22 = fmaf(vz, vz, c22);
    }
    float cov[6] = {c00, c10, c11, c20, c21, c22};
    float evals[3], nv[3];
    eigh3_lapack(cov, &Wall[tid * 27], evals, nv);
    float sv = evals[0] / ((evals[0] + evals[1]) + evals[2]);
    if (isG) {
        outNormG[q * 3 + 0] = nv[0];
        outNormG[q * 3 + 1] = nv[1];
        outNormG[q * 3 + 2] = nv[2];
        svG[q] = sv;
    } else {
        normP[q * 3 + 0] = nv[0];
        normP[q * 3 + 1] = nv[1];
        normP[q * 3 + 2] = nv[2];
        svP[q] = sv;
    }
}

// Final scalar losses.
__global__ void __launch_bounds__(256) kLoss(
        const float* __restrict__ normP, const float* __restrict__ svP,
        const float* __restrict__ svG, const float* __restrict__ normG,
        float* __restrict__ out) {
#pragma clang fp contract(off)
    __shared__ double sA[256];
    __shared__ double sB[256];
    int tid = threadIdx.x;
    double accN = 0.0, accS = 0.0;
    for (int q = tid; q < NQ; q += 256) {
        float ax = fabsf(normP[q * 3 + 0]) - fabsf(normG[q * 3 + 0]);
        float ay = fabsf(normP[q * 3 + 1]) - fabsf(normG[q * 3 + 1]);
        float az = fabsf(normP[q * 3 + 2]) - fabsf(normG[q * 3 + 2]);
        accN += (double)sqrtf(ax * ax + ay * ay + az * az);
        float ds = svP[q] - svG[q];
        accS += (double)(ds * ds);
    }
    sA[tid] = accN; sB[tid] = accS;
    __syncthreads();
    for (int s2 = 128; s2 > 0; s2 >>= 1) {
        if (tid < s2) { sA[tid] += sA[tid + s2]; sB[tid] += sB[tid + s2]; }
        __syncthreads();
    }
    if (tid == 0) {
        out[0] = (float)(sA[0] / (double)NQ);   // * W_NORMAL (=1)
        out[1] = (float)(sB[0] / (double)NQ);   // * W_SURFVAR (=1)
    }
}

extern "C" void kernel_launch(void* const* d_in, const int* in_sizes, int n_in,
                              void* d_out, int out_size, void* d_ws, size_t ws_size,
                              hipStream_t stream) {
    const float* pts = (const float*)d_in[0];
    const float* gtP = (const float*)d_in[1];
    const float* gtN = (const float*)d_in[2];
    float* out = (float*)d_out;
    float* ws = (float*)d_ws;

    float* idealW = ws;                        // NQ*3 floats
    int* idxG = (int*)(ws + NQ * 3);           // NQ*16 ints
    int* idxP = idxG + NQ * KNN;               // NQ*16 ints
    float* normP = (float*)(idxP + NQ * KNN);  // NQ*3 floats
    float* svG = normP + NQ * 3;               // NQ floats
    float* svP = svG + NQ;                     // NQ floats
    float* outNormG = out + 2;

    kAux<<<dim3(NQ / 8 + NQ / 32), dim3(256), 0, stream>>>(pts, gtP, gtN, idealW, idxP);
    kGlobalKNN<<<dim3(NQ / 8), dim3(256), 0, stream>>>(pts, idealW, idxG);
    kEigen<<<dim3(2 * NQ / 64), dim3(64), 0, stream>>>(pts, idxG, idxP,
                                                       outNormG, svG, normP, svP);
    kLoss<<<dim3(1), dim3(256), 0, stream>>>(normP, svP, svG, outNormG, out);
}